// Round 6
// baseline (789.486 us; speedup 1.0000x reference)
//
#include <hip/hip_runtime.h>
#include <math.h>

#define IN_DIM 128
#define OUT_DIM 64

typedef __attribute__((ext_vector_type(8))) short bf16x8;
typedef __attribute__((ext_vector_type(4))) float f32x4;
typedef __attribute__((ext_vector_type(4))) _Float16 half4;

__device__ __forceinline__ unsigned short f2bf(float f) {
    unsigned u = __float_as_uint(f);
    unsigned r = (u + 0x7FFFu + ((u >> 16) & 1u)) >> 16;   // RNE
    return (unsigned short)r;
}
__device__ __forceinline__ float bf2f(unsigned short h) {
    return __uint_as_float(((unsigned)h) << 16);
}

__device__ __forceinline__ void async_copy16(void* lds, const void* g) {
    __builtin_amdgcn_global_load_lds(
        (const __attribute__((address_space(1))) unsigned int*)g,
        (__attribute__((address_space(3))) unsigned int*)lds, 16, 0, 0);
}

// ---------------------------------------------------------------------------
// CSR build (by dst). Self-loops handled implicitly downstream.
// ---------------------------------------------------------------------------
__global__ void count_deg_kernel(const int* __restrict__ dst, int* __restrict__ deg, int e) {
    int i = blockIdx.x * blockDim.x + threadIdx.x;
    if (i < e) atomicAdd(&deg[dst[i]], 1);
}

__global__ __launch_bounds__(1024)
void scan_offsets_kernel(const int* __restrict__ deg, int* __restrict__ offs, int n) {
    __shared__ int partial[1024];
    const int tid = threadIdx.x;
    const int chunk = (n + 1023) / 1024;
    const int lo = tid * chunk;
    const int hi = min(lo + chunk, n);
    int s = 0;
    for (int i = lo; i < hi; ++i) s += deg[i];
    partial[tid] = s;
    __syncthreads();
    for (int d = 1; d < 1024; d <<= 1) {
        int v = (tid >= d) ? partial[tid - d] : 0;
        __syncthreads();
        partial[tid] += v;
        __syncthreads();
    }
    int run = (tid == 0) ? 0 : partial[tid - 1];
    for (int i = lo; i < hi; ++i) { offs[i] = run; run += deg[i]; }
    if (hi == n) offs[n] = run;
}

__global__ void scatter_edges_kernel(const int* __restrict__ src, const int* __restrict__ dst,
                                     const int* __restrict__ offs, int* __restrict__ cursor,
                                     int* __restrict__ esrc, int e) {
    int i = blockIdx.x * blockDim.x + threadIdx.x;
    if (i < e) {
        int d = dst[i];
        int pos = offs[d] + atomicAdd(&cursor[d], 1);
        esrc[pos] = src[i];
    }
}

// ---------------------------------------------------------------------------
// Split fp32 -> (hi, lo) bf16 for the layer-0 input x.
// ---------------------------------------------------------------------------
__global__ void split_x_kernel(const float* __restrict__ x,
                               unsigned short* __restrict__ hi, unsigned short* __restrict__ lo,
                               size_t n4) {
    size_t i = (size_t)blockIdx.x * blockDim.x + threadIdx.x;
    if (i >= n4) return;
    float4 v = *(const float4*)&x[i * 4];
    ushort4 h, l;
    h.x = f2bf(v.x); l.x = f2bf(v.x - bf2f(h.x));
    h.y = f2bf(v.y); l.y = f2bf(v.y - bf2f(h.y));
    h.z = f2bf(v.z); l.z = f2bf(v.z - bf2f(h.z));
    h.w = f2bf(v.w); l.w = f2bf(v.w - bf2f(h.w));
    *(ushort4*)&hi[i * 4] = h;
    *(ushort4*)&lo[i * 4] = l;
}

// ---------------------------------------------------------------------------
// W [K][Nc] fp32 -> Wt hi/lo [Nc][K] bf16 (transposed).
// ---------------------------------------------------------------------------
__global__ __launch_bounds__(256)
void transpose_split_kernel(const float* __restrict__ W,
                            unsigned short* __restrict__ hi, unsigned short* __restrict__ lo,
                            int K, int Nc) {
    __shared__ float t[32][33];
    const int k0 = blockIdx.x * 32, n0 = blockIdx.y * 32;
    const int tx = threadIdx.x, ty = threadIdx.y;   // (32,8)
    #pragma unroll
    for (int j = 0; j < 32; j += 8)
        t[ty + j][tx] = W[(size_t)(k0 + ty + j) * Nc + n0 + tx];
    __syncthreads();
    #pragma unroll
    for (int j = 0; j < 32; j += 8) {
        float v = t[tx][ty + j];
        unsigned short h = f2bf(v);
        hi[(size_t)(n0 + ty + j) * K + k0 + tx] = h;
        lo[(size_t)(n0 + ty + j) * K + k0 + tx] = f2bf(v - bf2f(h));
    }
}

// ---------------------------------------------------------------------------
// Split-bf16 MFMA GEMM, 128x128 tile, BK=32, 4 waves, 16x16x32 MFMA.
// BK=32 -> 32 KB LDS/step -> 4-5 blocks/CU so co-resident blocks hide the
// per-tile barrier drain (m114 overlap). LDS tile rows are 64 B; swizzle
// byte ^= ((row>>1)&3)<<4 (2-way bank aliasing = free), applied on the
// pre-swizzled global source (linear LDS dest) and on the ds_read side.
// Output: C16 head-major (layers 0-2) or fp32 row-major guarded (layer 3).
// ---------------------------------------------------------------------------
__global__ __launch_bounds__(256, 4)
void gemm_split_mfma(const unsigned short* __restrict__ Ahi, const unsigned short* __restrict__ Alo,
                     const unsigned short* __restrict__ Bhi, const unsigned short* __restrict__ Blo,
                     float* __restrict__ C, _Float16* __restrict__ C16,
                     int Nc, int K, size_t hstride16) {
    __shared__ char smem[32768];          // 4 tiles x [128 rows][64 B]
    char* sA_hi = smem;
    char* sA_lo = smem + 8192;
    char* sB_hi = smem + 16384;
    char* sB_lo = smem + 24576;

    const int tid = threadIdx.x;
    const int w = tid >> 6;
    const int lane = tid & 63;
    const int wr = w >> 1, wc = w & 1;
    const int brow = blockIdx.x * 128;
    const int bcol = blockIdx.y * 128;

    const size_t rb = (size_t)K * 2;

    // staging pattern: 2 instrs per lane per tile; linear LDS dest,
    // source pre-swizzled with byte ^= ((r>>1)&3)<<4 within the 64 B row
    int rr[2], bs[2], ldso[2];
    #pragma unroll
    for (int i = 0; i < 2; ++i) {
        int d = w * 2048 + i * 1024 + lane * 16;
        ldso[i] = d;
        rr[i] = d >> 6;
        bs[i] = (d & 63) ^ (((rr[i] >> 1) & 3) << 4);
    }

    const char* gA_hi = (const char*)Ahi + (size_t)brow * rb;
    const char* gA_lo = (const char*)Alo + (size_t)brow * rb;
    const char* gB_hi = (const char*)Bhi + (size_t)bcol * rb;
    const char* gB_lo = (const char*)Blo + (size_t)bcol * rb;

    f32x4 acc[4][4];
    #pragma unroll
    for (int i = 0; i < 4; ++i)
        #pragma unroll
        for (int j = 0; j < 4; ++j) acc[i][j] = (f32x4)0.f;

    for (int k0 = 0; k0 < K; k0 += 32) {
        __syncthreads();
        const size_t kb = (size_t)k0 * 2;
        #pragma unroll
        for (int i = 0; i < 2; ++i) {
            const size_t goff = (size_t)rr[i] * rb + kb + bs[i];
            async_copy16(sA_hi + ldso[i], gA_hi + goff);
            async_copy16(sA_lo + ldso[i], gA_lo + goff);
            async_copy16(sB_hi + ldso[i], gB_hi + goff);
            async_copy16(sB_lo + ldso[i], gB_lo + goff);
        }
        __syncthreads();

        bf16x8 a_hi[4], a_lo[4], b_hi[4], b_lo[4];
        const int kbyte = (lane >> 4) * 16;
        #pragma unroll
        for (int f = 0; f < 4; ++f) {
            const int ra = wr * 64 + f * 16 + (lane & 15);
            const int offA = ra * 64 + (kbyte ^ (((ra >> 1) & 3) << 4));
            a_hi[f] = *(const bf16x8*)(sA_hi + offA);
            a_lo[f] = *(const bf16x8*)(sA_lo + offA);
            const int rbn = wc * 64 + f * 16 + (lane & 15);
            const int offB = rbn * 64 + (kbyte ^ (((rbn >> 1) & 3) << 4));
            b_hi[f] = *(const bf16x8*)(sB_hi + offB);
            b_lo[f] = *(const bf16x8*)(sB_lo + offB);
        }
        #pragma unroll
        for (int m = 0; m < 4; ++m)
            #pragma unroll
            for (int n = 0; n < 4; ++n) {
                acc[m][n] = __builtin_amdgcn_mfma_f32_16x16x32_bf16(a_hi[m], b_hi[n], acc[m][n], 0, 0, 0);
                acc[m][n] = __builtin_amdgcn_mfma_f32_16x16x32_bf16(a_hi[m], b_lo[n], acc[m][n], 0, 0, 0);
                acc[m][n] = __builtin_amdgcn_mfma_f32_16x16x32_bf16(a_lo[m], b_hi[n], acc[m][n], 0, 0, 0);
            }
    }

    const int rowb = brow + wr * 64 + ((lane >> 4) * 4);
    const int colb = bcol + wc * 64 + (lane & 15);
    if (C16) {
        #pragma unroll
        for (int m = 0; m < 4; ++m)
            #pragma unroll
            for (int n = 0; n < 4; ++n) {
                const int col = colb + n * 16;
                const size_t base = (size_t)(col >> 8) * hstride16 + (size_t)(col & 255);
                #pragma unroll
                for (int j = 0; j < 4; ++j)
                    C16[base + (size_t)(rowb + m * 16 + j) * 256] = (_Float16)acc[m][n][j];
            }
    } else {
        #pragma unroll
        for (int m = 0; m < 4; ++m)
            #pragma unroll
            for (int n = 0; n < 4; ++n) {
                const int col = colb + n * 16;
                if (col < Nc) {
                    #pragma unroll
                    for (int j = 0; j < 4; ++j)
                        C[(size_t)(rowb + m * 16 + j) * Nc + col] = acc[m][n][j];
                }
            }
    }
}

// ---------------------------------------------------------------------------
// Attention logits, fp16 h (layers 0-2). h [4][hm][256]; out [4][N].
// ---------------------------------------------------------------------------
__global__ void alpha16_kernel(const _Float16* __restrict__ h, const float* __restrict__ a_src,
                               const float* __restrict__ a_dst,
                               float* __restrict__ as_out, float* __restrict__ ad_out,
                               int N, int hm) {
    const int n = blockIdx.x;
    const int w = threadIdx.x >> 6;
    const int lane = threadIdx.x & 63;
    const _Float16* hr = h + ((size_t)w * hm + n) * 256;
    half4 v = *(const half4*)(hr + lane * 4);
    float4 s4 = *(const float4*)(a_src + w * 256 + lane * 4);
    float4 d4 = *(const float4*)(a_dst + w * 256 + lane * 4);
    float ss = (float)v[0] * s4.x + (float)v[1] * s4.y + (float)v[2] * s4.z + (float)v[3] * s4.w;
    float sd = (float)v[0] * d4.x + (float)v[1] * d4.y + (float)v[2] * d4.z + (float)v[3] * d4.w;
    #pragma unroll
    for (int o = 32; o > 0; o >>= 1) { ss += __shfl_down(ss, o); sd += __shfl_down(sd, o); }
    if (lane == 0) {
        as_out[(size_t)w * N + n] = ss;
        ad_out[(size_t)w * N + n] = sd;
    }
}

// fp32 variant for layer 3 (1 head, CH=64)
__global__ void alpha32_kernel(const float* __restrict__ h, const float* __restrict__ a_src,
                               const float* __restrict__ a_dst,
                               float* __restrict__ as_out, float* __restrict__ ad_out, int N) {
    const int n = blockIdx.x;
    const int lane = threadIdx.x;
    float v = h[(size_t)n * 64 + lane];
    float ss = v * a_src[lane];
    float sd = v * a_dst[lane];
    #pragma unroll
    for (int o = 32; o > 0; o >>= 1) { ss += __shfl_down(ss, o); sd += __shfl_down(sd, o); }
    if (lane == 0) {
        as_out[n] = ss;
        ad_out[n] = sd;
    }
}

// ---------------------------------------------------------------------------
// Fused SpMM with in-wave softmax stats (removes logit_stats pass).
// One wave per (node, head): wave-parallel exact max & denom over the edge
// logits (butterfly reduce), then the unroll-4 weighted gather of fp16 rows.
// Epilogue: +bias, ELU, write bf16 hi/lo split.
// ---------------------------------------------------------------------------
__global__ __launch_bounds__(64)
void spmm16_kernel(const _Float16* __restrict__ h,   // [4][hm][256]
                   const float* __restrict__ as_,    // [4][N]
                   const float* __restrict__ ad_,
                   const int* __restrict__ offs, const int* __restrict__ esrc,
                   const float* __restrict__ bias,   // [4*256]
                   int N, int hm,
                   unsigned short* __restrict__ out_hi,
                   unsigned short* __restrict__ out_lo) {
    const int n = blockIdx.x;
    const int w = blockIdx.y;
    const int lane = threadIdx.x;

    const _Float16* hw = h + (size_t)w * hm * 256;
    const float* asw = as_ + (size_t)w * N;
    const float ad  = ad_[(size_t)w * N + n];

    float e0 = asw[n] + ad;
    e0 = (e0 > 0.f) ? e0 : 0.2f * e0;
    const int lo = offs[n], hi = offs[n + 1];

    // ---- wave-parallel stats: exact max, then denom ----
    float lmax = e0;
    for (int j = lo + lane; j < hi; j += 64) {
        float e = asw[esrc[j]] + ad;
        e = (e > 0.f) ? e : 0.2f * e;
        lmax = fmaxf(lmax, e);
    }
    #pragma unroll
    for (int o = 32; o > 0; o >>= 1) lmax = fmaxf(lmax, __shfl_xor(lmax, o));
    const float m = lmax;

    float lsum = (lane == 0) ? __expf(e0 - m) : 0.f;
    for (int j = lo + lane; j < hi; j += 64) {
        float e = asw[esrc[j]] + ad;
        e = (e > 0.f) ? e : 0.2f * e;
        lsum += __expf(e - m);
    }
    #pragma unroll
    for (int o = 32; o > 0; o >>= 1) lsum += __shfl_xor(lsum, o);
    const float inv = 1.0f / (lsum + 1e-16f);

    // ---- weighted gather ----
    float acc0, acc1, acc2, acc3;
    {
        const float p0 = __expf(e0 - m) * inv;
        half4 t = *(const half4*)(hw + (size_t)n * 256 + lane * 4);
        acc0 = p0 * (float)t[0]; acc1 = p0 * (float)t[1];
        acc2 = p0 * (float)t[2]; acc3 = p0 * (float)t[3];
    }

    int j = lo;
    for (; j + 4 <= hi; j += 4) {
        const int s0 = esrc[j], s1 = esrc[j + 1], s2 = esrc[j + 2], s3 = esrc[j + 3];
        const half4 r0 = *(const half4*)(hw + (size_t)s0 * 256 + lane * 4);
        const half4 r1 = *(const half4*)(hw + (size_t)s1 * 256 + lane * 4);
        const half4 r2 = *(const half4*)(hw + (size_t)s2 * 256 + lane * 4);
        const half4 r3 = *(const half4*)(hw + (size_t)s3 * 256 + lane * 4);
        float e, p0, p1, p2, p3;
        e = asw[s0] + ad; e = (e > 0.f) ? e : 0.2f * e; p0 = __expf(e - m) * inv;
        e = asw[s1] + ad; e = (e > 0.f) ? e : 0.2f * e; p1 = __expf(e - m) * inv;
        e = asw[s2] + ad; e = (e > 0.f) ? e : 0.2f * e; p2 = __expf(e - m) * inv;
        e = asw[s3] + ad; e = (e > 0.f) ? e : 0.2f * e; p3 = __expf(e - m) * inv;
        acc0 += p0 * (float)r0[0] + p1 * (float)r1[0] + p2 * (float)r2[0] + p3 * (float)r3[0];
        acc1 += p0 * (float)r0[1] + p1 * (float)r1[1] + p2 * (float)r2[1] + p3 * (float)r3[1];
        acc2 += p0 * (float)r0[2] + p1 * (float)r1[2] + p2 * (float)r2[2] + p3 * (float)r3[2];
        acc3 += p0 * (float)r0[3] + p1 * (float)r1[3] + p2 * (float)r2[3] + p3 * (float)r3[3];
    }
    for (; j < hi; ++j) {
        const int s = esrc[j];
        float e = asw[s] + ad;
        e = (e > 0.f) ? e : 0.2f * e;
        const float p = __expf(e - m) * inv;
        half4 t = *(const half4*)(hw + (size_t)s * 256 + lane * 4);
        acc0 += p * (float)t[0]; acc1 += p * (float)t[1];
        acc2 += p * (float)t[2]; acc3 += p * (float)t[3];
    }

    float v0 = acc0 + bias[w * 256 + lane * 4 + 0];
    float v1 = acc1 + bias[w * 256 + lane * 4 + 1];
    float v2 = acc2 + bias[w * 256 + lane * 4 + 2];
    float v3 = acc3 + bias[w * 256 + lane * 4 + 3];
    v0 = (v0 > 0.f) ? v0 : (__expf(v0) - 1.0f);
    v1 = (v1 > 0.f) ? v1 : (__expf(v1) - 1.0f);
    v2 = (v2 > 0.f) ? v2 : (__expf(v2) - 1.0f);
    v3 = (v3 > 0.f) ? v3 : (__expf(v3) - 1.0f);

    const size_t o = (size_t)n * 1024 + (size_t)w * 256 + lane * 4;
    ushort4 hv, lv;
    hv.x = f2bf(v0); lv.x = f2bf(v0 - bf2f(hv.x));
    hv.y = f2bf(v1); lv.y = f2bf(v1 - bf2f(hv.y));
    hv.z = f2bf(v2); lv.z = f2bf(v2 - bf2f(hv.z));
    hv.w = f2bf(v3); lv.w = f2bf(v3 - bf2f(hv.w));
    *(ushort4*)&out_hi[o] = hv;
    *(ushort4*)&out_lo[o] = lv;
}

// ---------------------------------------------------------------------------
// Final layer: fp32 h [N][64], 1 head, no ELU, fp32 out. Fused stats.
// ---------------------------------------------------------------------------
__global__ __launch_bounds__(64)
void spmm32_kernel(const float* __restrict__ h,
                   const float* __restrict__ as_, const float* __restrict__ ad_,
                   const int* __restrict__ offs, const int* __restrict__ esrc,
                   const float* __restrict__ bias,
                   int N, float* __restrict__ out) {
    const int n = blockIdx.x;
    const int lane = threadIdx.x;

    const float ad  = ad_[n];
    float e0 = as_[n] + ad;
    e0 = (e0 > 0.f) ? e0 : 0.2f * e0;
    const int lo = offs[n], hi = offs[n + 1];

    float lmax = e0;
    for (int j = lo + lane; j < hi; j += 64) {
        float e = as_[esrc[j]] + ad;
        e = (e > 0.f) ? e : 0.2f * e;
        lmax = fmaxf(lmax, e);
    }
    #pragma unroll
    for (int o = 32; o > 0; o >>= 1) lmax = fmaxf(lmax, __shfl_xor(lmax, o));
    const float m = lmax;

    float lsum = (lane == 0) ? __expf(e0 - m) : 0.f;
    for (int j = lo + lane; j < hi; j += 64) {
        float e = as_[esrc[j]] + ad;
        e = (e > 0.f) ? e : 0.2f * e;
        lsum += __expf(e - m);
    }
    #pragma unroll
    for (int o = 32; o > 0; o >>= 1) lsum += __shfl_xor(lsum, o);
    const float inv = 1.0f / (lsum + 1e-16f);

    float acc;
    {
        const float p0 = __expf(e0 - m) * inv;
        acc = p0 * h[(size_t)n * 64 + lane];
    }

    int j = lo;
    for (; j + 4 <= hi; j += 4) {
        const int s0 = esrc[j], s1 = esrc[j + 1], s2 = esrc[j + 2], s3 = esrc[j + 3];
        const float r0 = h[(size_t)s0 * 64 + lane];
        const float r1 = h[(size_t)s1 * 64 + lane];
        const float r2 = h[(size_t)s2 * 64 + lane];
        const float r3 = h[(size_t)s3 * 64 + lane];
        float e, p0, p1, p2, p3;
        e = as_[s0] + ad; e = (e > 0.f) ? e : 0.2f * e; p0 = __expf(e - m) * inv;
        e = as_[s1] + ad; e = (e > 0.f) ? e : 0.2f * e; p1 = __expf(e - m) * inv;
        e = as_[s2] + ad; e = (e > 0.f) ? e : 0.2f * e; p2 = __expf(e - m) * inv;
        e = as_[s3] + ad; e = (e > 0.f) ? e : 0.2f * e; p3 = __expf(e - m) * inv;
        acc += p0 * r0 + p1 * r1 + p2 * r2 + p3 * r3;
    }
    for (; j < hi; ++j) {
        const int s = esrc[j];
        float e = as_[s] + ad;
        e = (e > 0.f) ? e : 0.2f * e;
        const float p = __expf(e - m) * inv;
        acc += p * h[(size_t)s * 64 + lane];
    }

    out[(size_t)n * 64 + lane] = acc + bias[lane];
}

// ---------------------------------------------------------------------------
extern "C" void kernel_launch(void* const* d_in, const int* in_sizes, int n_in,
                              void* d_out, int out_size, void* d_ws, size_t ws_size,
                              hipStream_t stream) {
    const float* x    = (const float*)d_in[0];
    const int*   edge = (const int*)d_in[1];
    const int N = in_sizes[0] / IN_DIM;
    const int E = in_sizes[1] / 2;
    const int Mp = ((N + 127) / 128) * 128;

    const float* W[4]; const float* As[4]; const float* Ad[4]; const float* Bb[4];
    for (int i = 0; i < 4; ++i) {
        W[i]  = (const float*)d_in[2 + 4 * i];
        As[i] = (const float*)d_in[3 + 4 * i];
        Ad[i] = (const float*)d_in[4 + 4 * i];
        Bb[i] = (const float*)d_in[5 + 4 * i];
    }

    char* ws = (char*)d_ws;
    auto alloc = [&](size_t bytes) {
        char* p = ws;
        ws += (bytes + 255) & ~(size_t)255;
        return p;
    };
    _Float16*       h16   = (_Float16*)alloc((size_t)4 * Mp * 256 * 2);    // h, fp16 head-major
    float*          bufA  = (float*)alloc((size_t)Mp * OUT_DIM * 4);       // layer-3 GEMM out
    unsigned short* Xhi   = (unsigned short*)alloc((size_t)Mp * 1024 * 2);
    unsigned short* Xlo   = (unsigned short*)alloc((size_t)Mp * 1024 * 2);
    unsigned short* Wthi  = (unsigned short*)alloc((size_t)1024 * 1024 * 2);
    unsigned short* Wtlo  = (unsigned short*)alloc((size_t)1024 * 1024 * 2);
    float*          as_buf = (float*)alloc((size_t)N * 4 * 4);
    float*          ad_buf = (float*)alloc((size_t)N * 4 * 4);
    int*            deg    = (int*)alloc((size_t)(N + 1) * 4);
    int*            offs   = (int*)alloc((size_t)(N + 1) * 4);
    int*            cursor = (int*)alloc((size_t)N * 4);
    int*            esrc   = (int*)alloc((size_t)E * 4);
    (void)ws_size;

    const int* e_src = edge;
    const int* e_dst = edge + E;

    // ---- CSR build ----
    hipMemsetAsync(deg, 0, (size_t)N * 4, stream);
    count_deg_kernel<<<(E + 255) / 256, 256, 0, stream>>>(e_dst, deg, E);
    scan_offsets_kernel<<<1, 1024, 0, stream>>>(deg, offs, N);
    hipMemsetAsync(cursor, 0, (size_t)N * 4, stream);
    scatter_edges_kernel<<<(E + 255) / 256, 256, 0, stream>>>(e_src, e_dst, offs, cursor, esrc, E);

    // ---- zero only the pad rows of the split A views ----
    hipMemsetAsync((char*)Xhi + (size_t)N * 256, 0, (size_t)(Mp - N) * 256, stream);
    hipMemsetAsync((char*)Xlo + (size_t)N * 256, 0, (size_t)(Mp - N) * 256, stream);
    hipMemsetAsync((char*)Xhi + (size_t)N * 2048, 0, (size_t)(Mp - N) * 2048, stream);
    hipMemsetAsync((char*)Xlo + (size_t)N * 2048, 0, (size_t)(Mp - N) * 2048, stream);

    // ---- layer 0 input split ----
    {
        size_t n4 = (size_t)N * IN_DIM / 4;
        split_x_kernel<<<(unsigned)((n4 + 255) / 256), 256, 0, stream>>>(x, Xhi, Xlo, n4);
    }

    const dim3 tblk(32, 8);
    const int gx = Mp / 128;
    const size_t hstride16 = (size_t)Mp * 256;

    // ---- Layer 0 ----
    transpose_split_kernel<<<dim3(IN_DIM / 32, 1024 / 32), tblk, 0, stream>>>(W[0], Wthi, Wtlo, IN_DIM, 1024);
    gemm_split_mfma<<<dim3(gx, 8), 256, 0, stream>>>(Xhi, Xlo, Wthi, Wtlo, nullptr, h16, 1024, IN_DIM, hstride16);
    alpha16_kernel<<<N, 256, 0, stream>>>(h16, As[0], Ad[0], as_buf, ad_buf, N, Mp);
    spmm16_kernel<<<dim3(N, 4), 64, 0, stream>>>(
        h16, as_buf, ad_buf, offs, esrc, Bb[0], N, Mp, Xhi, Xlo);

    // ---- Layers 1,2 ----
    for (int l = 1; l <= 2; ++l) {
        transpose_split_kernel<<<dim3(1024 / 32, 1024 / 32), tblk, 0, stream>>>(W[l], Wthi, Wtlo, 1024, 1024);
        gemm_split_mfma<<<dim3(gx, 8), 256, 0, stream>>>(Xhi, Xlo, Wthi, Wtlo, nullptr, h16, 1024, 1024, hstride16);
        alpha16_kernel<<<N, 256, 0, stream>>>(h16, As[l], Ad[l], as_buf, ad_buf, N, Mp);
        spmm16_kernel<<<dim3(N, 4), 64, 0, stream>>>(
            h16, as_buf, ad_buf, offs, esrc, Bb[l], N, Mp, Xhi, Xlo);
    }

    // ---- Layer 3: K=1024 -> h(64), 1 head, fp32 out ----
    hipMemsetAsync(Wthi, 0, (size_t)128 * 1024 * 2, stream);
    hipMemsetAsync(Wtlo, 0, (size_t)128 * 1024 * 2, stream);
    transpose_split_kernel<<<dim3(1024 / 32, OUT_DIM / 32), tblk, 0, stream>>>(W[3], Wthi, Wtlo, 1024, OUT_DIM);
    gemm_split_mfma<<<dim3(gx, 1), 256, 0, stream>>>(Xhi, Xlo, Wthi, Wtlo, bufA, nullptr, OUT_DIM, 1024, 0);
    alpha32_kernel<<<N, 64, 0, stream>>>(bufA, As[3], Ad[3], as_buf, ad_buf, N);
    spmm32_kernel<<<N, 64, 0, stream>>>(
        bufA, as_buf, ad_buf, offs, esrc, Bb[3], N, (float*)d_out);
}

// Round 7
// 722.692 us; speedup vs baseline: 1.0924x; 1.0924x over previous
//
#include <hip/hip_runtime.h>
#include <math.h>

#define IN_DIM 128
#define OUT_DIM 64

typedef __attribute__((ext_vector_type(8))) short bf16x8;
typedef __attribute__((ext_vector_type(4))) float f32x4;
typedef __attribute__((ext_vector_type(4))) _Float16 half4;

__device__ __forceinline__ unsigned short f2bf(float f) {
    unsigned u = __float_as_uint(f);
    unsigned r = (u + 0x7FFFu + ((u >> 16) & 1u)) >> 16;   // RNE
    return (unsigned short)r;
}
__device__ __forceinline__ float bf2f(unsigned short h) {
    return __uint_as_float(((unsigned)h) << 16);
}

__device__ __forceinline__ void async_copy16(void* lds, const void* g) {
    __builtin_amdgcn_global_load_lds(
        (const __attribute__((address_space(1))) unsigned int*)g,
        (__attribute__((address_space(3))) unsigned int*)lds, 16, 0, 0);
}

// ---------------------------------------------------------------------------
// CSR build (by dst). Self-loops handled implicitly downstream.
// ---------------------------------------------------------------------------
__global__ void count_deg_kernel(const int* __restrict__ dst, int* __restrict__ deg, int e) {
    int i = blockIdx.x * blockDim.x + threadIdx.x;
    if (i < e) atomicAdd(&deg[dst[i]], 1);
}

__global__ __launch_bounds__(1024)
void scan_offsets_kernel(const int* __restrict__ deg, int* __restrict__ offs, int n) {
    __shared__ int partial[1024];
    const int tid = threadIdx.x;
    const int chunk = (n + 1023) / 1024;
    const int lo = tid * chunk;
    const int hi = min(lo + chunk, n);
    int s = 0;
    for (int i = lo; i < hi; ++i) s += deg[i];
    partial[tid] = s;
    __syncthreads();
    for (int d = 1; d < 1024; d <<= 1) {
        int v = (tid >= d) ? partial[tid - d] : 0;
        __syncthreads();
        partial[tid] += v;
        __syncthreads();
    }
    int run = (tid == 0) ? 0 : partial[tid - 1];
    for (int i = lo; i < hi; ++i) { offs[i] = run; run += deg[i]; }
    if (hi == n) offs[n] = run;
}

__global__ void scatter_edges_kernel(const int* __restrict__ src, const int* __restrict__ dst,
                                     const int* __restrict__ offs, int* __restrict__ cursor,
                                     int* __restrict__ esrc, int e) {
    int i = blockIdx.x * blockDim.x + threadIdx.x;
    if (i < e) {
        int d = dst[i];
        int pos = offs[d] + atomicAdd(&cursor[d], 1);
        esrc[pos] = src[i];
    }
}

// ---------------------------------------------------------------------------
// Split fp32 -> (hi, lo) bf16 for the layer-0 input x.
// ---------------------------------------------------------------------------
__global__ void split_x_kernel(const float* __restrict__ x,
                               unsigned short* __restrict__ hi, unsigned short* __restrict__ lo,
                               size_t n4) {
    size_t i = (size_t)blockIdx.x * blockDim.x + threadIdx.x;
    if (i >= n4) return;
    float4 v = *(const float4*)&x[i * 4];
    ushort4 h, l;
    h.x = f2bf(v.x); l.x = f2bf(v.x - bf2f(h.x));
    h.y = f2bf(v.y); l.y = f2bf(v.y - bf2f(h.y));
    h.z = f2bf(v.z); l.z = f2bf(v.z - bf2f(h.z));
    h.w = f2bf(v.w); l.w = f2bf(v.w - bf2f(h.w));
    *(ushort4*)&hi[i * 4] = h;
    *(ushort4*)&lo[i * 4] = l;
}

// ---------------------------------------------------------------------------
// W [K][Nc] fp32 -> Wt hi/lo [Nc][K] bf16 (transposed).
// ---------------------------------------------------------------------------
__global__ __launch_bounds__(256)
void transpose_split_kernel(const float* __restrict__ W,
                            unsigned short* __restrict__ hi, unsigned short* __restrict__ lo,
                            int K, int Nc) {
    __shared__ float t[32][33];
    const int k0 = blockIdx.x * 32, n0 = blockIdx.y * 32;
    const int tx = threadIdx.x, ty = threadIdx.y;   // (32,8)
    #pragma unroll
    for (int j = 0; j < 32; j += 8)
        t[ty + j][tx] = W[(size_t)(k0 + ty + j) * Nc + n0 + tx];
    __syncthreads();
    #pragma unroll
    for (int j = 0; j < 32; j += 8) {
        float v = t[tx][ty + j];
        unsigned short h = f2bf(v);
        hi[(size_t)(n0 + ty + j) * K + k0 + tx] = h;
        lo[(size_t)(n0 + ty + j) * K + k0 + tx] = f2bf(v - bf2f(h));
    }
}

// ---------------------------------------------------------------------------
// Split-bf16 MFMA GEMM, 128x128 tile, BK=64, 4 waves, 16x16x32 MFMA.
// (R5 structure: 64 KB LDS, 2 blocks/CU, 16 in-flight global_load_lds/wave —
//  BK=32 variant regressed, see R6.)
// Output: C16 head-major [4][Mp][256] (layers 0-2) or fp32 row-major (layer 3).
// Fused alpha epilogue (C16 path, as_out!=nullptr): per-thread partial dots
// of the exact fp32 acc tile with a_src/a_dst, 16-lane shfl_xor reduce,
// one atomicAdd per (head,row) per block-half. Removes the alpha16 pass.
// ---------------------------------------------------------------------------
__global__ __launch_bounds__(256, 2)
void gemm_split_mfma(const unsigned short* __restrict__ Ahi, const unsigned short* __restrict__ Alo,
                     const unsigned short* __restrict__ Bhi, const unsigned short* __restrict__ Blo,
                     float* __restrict__ C, _Float16* __restrict__ C16,
                     int Nc, int K, size_t hstride16,
                     const float* __restrict__ Asrc, const float* __restrict__ Adst,
                     float* __restrict__ as_out, float* __restrict__ ad_out, int Nrows) {
    __shared__ char smem[65536];          // 4 tiles x [128 rows][128 B]
    char* sA_hi = smem;
    char* sA_lo = smem + 16384;
    char* sB_hi = smem + 32768;
    char* sB_lo = smem + 49152;

    const int tid = threadIdx.x;
    const int w = tid >> 6;
    const int lane = tid & 63;
    const int wr = w >> 1, wc = w & 1;
    const int brow = blockIdx.x * 128;
    const int bcol = blockIdx.y * 128;

    const size_t rb = (size_t)K * 2;

    int rr[4], bs[4], ldso[4];
    #pragma unroll
    for (int i = 0; i < 4; ++i) {
        int d = w * 4096 + i * 1024 + lane * 16;
        ldso[i] = d;
        rr[i] = d >> 7;
        int b = d & 127;
        bs[i] = b ^ ((rr[i] & 7) << 4);
    }

    const char* gA_hi = (const char*)Ahi + (size_t)brow * rb;
    const char* gA_lo = (const char*)Alo + (size_t)brow * rb;
    const char* gB_hi = (const char*)Bhi + (size_t)bcol * rb;
    const char* gB_lo = (const char*)Blo + (size_t)bcol * rb;

    f32x4 acc[4][4];
    #pragma unroll
    for (int i = 0; i < 4; ++i)
        #pragma unroll
        for (int j = 0; j < 4; ++j) acc[i][j] = (f32x4)0.f;

    for (int k0 = 0; k0 < K; k0 += 64) {
        __syncthreads();
        const size_t kb = (size_t)k0 * 2;
        #pragma unroll
        for (int i = 0; i < 4; ++i) {
            const size_t goff = (size_t)rr[i] * rb + kb + bs[i];
            async_copy16(sA_hi + ldso[i], gA_hi + goff);
            async_copy16(sA_lo + ldso[i], gA_lo + goff);
            async_copy16(sB_hi + ldso[i], gB_hi + goff);
            async_copy16(sB_lo + ldso[i], gB_lo + goff);
        }
        __syncthreads();

        #pragma unroll
        for (int kk = 0; kk < 2; ++kk) {
            bf16x8 a_hi[4], a_lo[4], b_hi[4], b_lo[4];
            const int kbyte = kk * 64 + ((lane >> 4) * 16);
            #pragma unroll
            for (int f = 0; f < 4; ++f) {
                const int ra = wr * 64 + f * 16 + (lane & 15);
                const int offA = ra * 128 + (kbyte ^ ((ra & 7) << 4));
                a_hi[f] = *(const bf16x8*)(sA_hi + offA);
                a_lo[f] = *(const bf16x8*)(sA_lo + offA);
                const int rbn = wc * 64 + f * 16 + (lane & 15);
                const int offB = rbn * 128 + (kbyte ^ ((rbn & 7) << 4));
                b_hi[f] = *(const bf16x8*)(sB_hi + offB);
                b_lo[f] = *(const bf16x8*)(sB_lo + offB);
            }
            #pragma unroll
            for (int m = 0; m < 4; ++m)
                #pragma unroll
                for (int n = 0; n < 4; ++n) {
                    acc[m][n] = __builtin_amdgcn_mfma_f32_16x16x32_bf16(a_hi[m], b_hi[n], acc[m][n], 0, 0, 0);
                    acc[m][n] = __builtin_amdgcn_mfma_f32_16x16x32_bf16(a_hi[m], b_lo[n], acc[m][n], 0, 0, 0);
                    acc[m][n] = __builtin_amdgcn_mfma_f32_16x16x32_bf16(a_lo[m], b_hi[n], acc[m][n], 0, 0, 0);
                }
        }
    }

    const int rowb = brow + wr * 64 + ((lane >> 4) * 4);
    const int colb = bcol + wc * 64 + (lane & 15);
    if (C16) {
        #pragma unroll
        for (int m = 0; m < 4; ++m)
            #pragma unroll
            for (int n = 0; n < 4; ++n) {
                const int col = colb + n * 16;
                const size_t base = (size_t)(col >> 8) * hstride16 + (size_t)(col & 255);
                #pragma unroll
                for (int j = 0; j < 4; ++j)
                    C16[base + (size_t)(rowb + m * 16 + j) * 256] = (_Float16)acc[m][n][j];
            }
        if (as_out) {
            // fused alpha: dot of acc tile with a_src/a_dst over this block's cols
            const int lcol = lane & 15;
            const int cb = bcol + wc * 64;       // 64-aligned, within one head
            const int head = cb >> 8;
            float as4[4], ad4[4];
            #pragma unroll
            for (int n = 0; n < 4; ++n) {
                as4[n] = Asrc[cb + n * 16 + lcol];
                ad4[n] = Adst[cb + n * 16 + lcol];
            }
            #pragma unroll
            for (int m = 0; m < 4; ++m)
                #pragma unroll
                for (int j = 0; j < 4; ++j) {
                    float ps = acc[m][0][j] * as4[0] + acc[m][1][j] * as4[1]
                             + acc[m][2][j] * as4[2] + acc[m][3][j] * as4[3];
                    float pd = acc[m][0][j] * ad4[0] + acc[m][1][j] * ad4[1]
                             + acc[m][2][j] * ad4[2] + acc[m][3][j] * ad4[3];
                    #pragma unroll
                    for (int o = 1; o < 16; o <<= 1) {
                        ps += __shfl_xor(ps, o);
                        pd += __shfl_xor(pd, o);
                    }
                    if (lcol == 0) {
                        const int row = rowb + m * 16 + j;
                        if (row < Nrows) {
                            atomicAdd(&as_out[(size_t)head * Nrows + row], ps);
                            atomicAdd(&ad_out[(size_t)head * Nrows + row], pd);
                        }
                    }
                }
        }
    } else {
        #pragma unroll
        for (int m = 0; m < 4; ++m)
            #pragma unroll
            for (int n = 0; n < 4; ++n) {
                const int col = colb + n * 16;
                if (col < Nc) {
                    #pragma unroll
                    for (int j = 0; j < 4; ++j)
                        C[(size_t)(rowb + m * 16 + j) * Nc + col] = acc[m][n][j];
                }
            }
    }
}

// ---------------------------------------------------------------------------
// fp32 alpha for layer 3 (1 head, CH=64)
// ---------------------------------------------------------------------------
__global__ void alpha32_kernel(const float* __restrict__ h, const float* __restrict__ a_src,
                               const float* __restrict__ a_dst,
                               float* __restrict__ as_out, float* __restrict__ ad_out, int N) {
    const int n = blockIdx.x;
    const int lane = threadIdx.x;
    float v = h[(size_t)n * 64 + lane];
    float ss = v * a_src[lane];
    float sd = v * a_dst[lane];
    #pragma unroll
    for (int o = 32; o > 0; o >>= 1) { ss += __shfl_down(ss, o); sd += __shfl_down(sd, o); }
    if (lane == 0) {
        as_out[n] = ss;
        ad_out[n] = sd;
    }
}

// ---------------------------------------------------------------------------
// Fused SpMM with in-wave softmax stats. One wave per (node, head):
// wave-parallel exact max & denom over edge logits, then unroll-4 weighted
// gather of fp16 rows. Epilogue: +bias, ELU, bf16 hi/lo split write.
// ---------------------------------------------------------------------------
__global__ __launch_bounds__(64)
void spmm16_kernel(const _Float16* __restrict__ h,   // [4][hm][256]
                   const float* __restrict__ as_,    // [4][N]
                   const float* __restrict__ ad_,
                   const int* __restrict__ offs, const int* __restrict__ esrc,
                   const float* __restrict__ bias,   // [4*256]
                   int N, int hm,
                   unsigned short* __restrict__ out_hi,
                   unsigned short* __restrict__ out_lo) {
    const int n = blockIdx.x;
    const int w = blockIdx.y;
    const int lane = threadIdx.x;

    const _Float16* hw = h + (size_t)w * hm * 256;
    const float* asw = as_ + (size_t)w * N;
    const float ad  = ad_[(size_t)w * N + n];

    float e0 = asw[n] + ad;
    e0 = (e0 > 0.f) ? e0 : 0.2f * e0;
    const int lo = offs[n], hi = offs[n + 1];

    // ---- wave-parallel stats: exact max, then denom ----
    float lmax = e0;
    for (int j = lo + lane; j < hi; j += 64) {
        float e = asw[esrc[j]] + ad;
        e = (e > 0.f) ? e : 0.2f * e;
        lmax = fmaxf(lmax, e);
    }
    #pragma unroll
    for (int o = 32; o > 0; o >>= 1) lmax = fmaxf(lmax, __shfl_xor(lmax, o));
    const float m = lmax;

    float lsum = (lane == 0) ? __expf(e0 - m) : 0.f;
    for (int j = lo + lane; j < hi; j += 64) {
        float e = asw[esrc[j]] + ad;
        e = (e > 0.f) ? e : 0.2f * e;
        lsum += __expf(e - m);
    }
    #pragma unroll
    for (int o = 32; o > 0; o >>= 1) lsum += __shfl_xor(lsum, o);
    const float inv = 1.0f / (lsum + 1e-16f);

    // ---- weighted gather ----
    float acc0, acc1, acc2, acc3;
    {
        const float p0 = __expf(e0 - m) * inv;
        half4 t = *(const half4*)(hw + (size_t)n * 256 + lane * 4);
        acc0 = p0 * (float)t[0]; acc1 = p0 * (float)t[1];
        acc2 = p0 * (float)t[2]; acc3 = p0 * (float)t[3];
    }

    int j = lo;
    for (; j + 4 <= hi; j += 4) {
        const int s0 = esrc[j], s1 = esrc[j + 1], s2 = esrc[j + 2], s3 = esrc[j + 3];
        const half4 r0 = *(const half4*)(hw + (size_t)s0 * 256 + lane * 4);
        const half4 r1 = *(const half4*)(hw + (size_t)s1 * 256 + lane * 4);
        const half4 r2 = *(const half4*)(hw + (size_t)s2 * 256 + lane * 4);
        const half4 r3 = *(const half4*)(hw + (size_t)s3 * 256 + lane * 4);
        float e, p0, p1, p2, p3;
        e = asw[s0] + ad; e = (e > 0.f) ? e : 0.2f * e; p0 = __expf(e - m) * inv;
        e = asw[s1] + ad; e = (e > 0.f) ? e : 0.2f * e; p1 = __expf(e - m) * inv;
        e = asw[s2] + ad; e = (e > 0.f) ? e : 0.2f * e; p2 = __expf(e - m) * inv;
        e = asw[s3] + ad; e = (e > 0.f) ? e : 0.2f * e; p3 = __expf(e - m) * inv;
        acc0 += p0 * (float)r0[0] + p1 * (float)r1[0] + p2 * (float)r2[0] + p3 * (float)r3[0];
        acc1 += p0 * (float)r0[1] + p1 * (float)r1[1] + p2 * (float)r2[1] + p3 * (float)r3[1];
        acc2 += p0 * (float)r0[2] + p1 * (float)r1[2] + p2 * (float)r2[2] + p3 * (float)r3[2];
        acc3 += p0 * (float)r0[3] + p1 * (float)r1[3] + p2 * (float)r2[3] + p3 * (float)r3[3];
    }
    for (; j < hi; ++j) {
        const int s = esrc[j];
        float e = asw[s] + ad;
        e = (e > 0.f) ? e : 0.2f * e;
        const float p = __expf(e - m) * inv;
        half4 t = *(const half4*)(hw + (size_t)s * 256 + lane * 4);
        acc0 += p * (float)t[0]; acc1 += p * (float)t[1];
        acc2 += p * (float)t[2]; acc3 += p * (float)t[3];
    }

    float v0 = acc0 + bias[w * 256 + lane * 4 + 0];
    float v1 = acc1 + bias[w * 256 + lane * 4 + 1];
    float v2 = acc2 + bias[w * 256 + lane * 4 + 2];
    float v3 = acc3 + bias[w * 256 + lane * 4 + 3];
    v0 = (v0 > 0.f) ? v0 : (__expf(v0) - 1.0f);
    v1 = (v1 > 0.f) ? v1 : (__expf(v1) - 1.0f);
    v2 = (v2 > 0.f) ? v2 : (__expf(v2) - 1.0f);
    v3 = (v3 > 0.f) ? v3 : (__expf(v3) - 1.0f);

    const size_t o = (size_t)n * 1024 + (size_t)w * 256 + lane * 4;
    ushort4 hv, lv;
    hv.x = f2bf(v0); lv.x = f2bf(v0 - bf2f(hv.x));
    hv.y = f2bf(v1); lv.y = f2bf(v1 - bf2f(hv.y));
    hv.z = f2bf(v2); lv.z = f2bf(v2 - bf2f(hv.z));
    hv.w = f2bf(v3); lv.w = f2bf(v3 - bf2f(hv.w));
    *(ushort4*)&out_hi[o] = hv;
    *(ushort4*)&out_lo[o] = lv;
}

// ---------------------------------------------------------------------------
// Final layer: fp32 h [N][64], 1 head, no ELU, fp32 out. Fused stats.
// ---------------------------------------------------------------------------
__global__ __launch_bounds__(64)
void spmm32_kernel(const float* __restrict__ h,
                   const float* __restrict__ as_, const float* __restrict__ ad_,
                   const int* __restrict__ offs, const int* __restrict__ esrc,
                   const float* __restrict__ bias,
                   int N, float* __restrict__ out) {
    const int n = blockIdx.x;
    const int lane = threadIdx.x;

    const float ad  = ad_[n];
    float e0 = as_[n] + ad;
    e0 = (e0 > 0.f) ? e0 : 0.2f * e0;
    const int lo = offs[n], hi = offs[n + 1];

    float lmax = e0;
    for (int j = lo + lane; j < hi; j += 64) {
        float e = as_[esrc[j]] + ad;
        e = (e > 0.f) ? e : 0.2f * e;
        lmax = fmaxf(lmax, e);
    }
    #pragma unroll
    for (int o = 32; o > 0; o >>= 1) lmax = fmaxf(lmax, __shfl_xor(lmax, o));
    const float m = lmax;

    float lsum = (lane == 0) ? __expf(e0 - m) : 0.f;
    for (int j = lo + lane; j < hi; j += 64) {
        float e = as_[esrc[j]] + ad;
        e = (e > 0.f) ? e : 0.2f * e;
        lsum += __expf(e - m);
    }
    #pragma unroll
    for (int o = 32; o > 0; o >>= 1) lsum += __shfl_xor(lsum, o);
    const float inv = 1.0f / (lsum + 1e-16f);

    float acc;
    {
        const float p0 = __expf(e0 - m) * inv;
        acc = p0 * h[(size_t)n * 64 + lane];
    }

    int j = lo;
    for (; j + 4 <= hi; j += 4) {
        const int s0 = esrc[j], s1 = esrc[j + 1], s2 = esrc[j + 2], s3 = esrc[j + 3];
        const float r0 = h[(size_t)s0 * 64 + lane];
        const float r1 = h[(size_t)s1 * 64 + lane];
        const float r2 = h[(size_t)s2 * 64 + lane];
        const float r3 = h[(size_t)s3 * 64 + lane];
        float e, p0, p1, p2, p3;
        e = as_[s0] + ad; e = (e > 0.f) ? e : 0.2f * e; p0 = __expf(e - m) * inv;
        e = as_[s1] + ad; e = (e > 0.f) ? e : 0.2f * e; p1 = __expf(e - m) * inv;
        e = as_[s2] + ad; e = (e > 0.f) ? e : 0.2f * e; p2 = __expf(e - m) * inv;
        e = as_[s3] + ad; e = (e > 0.f) ? e : 0.2f * e; p3 = __expf(e - m) * inv;
        acc += p0 * r0 + p1 * r1 + p2 * r2 + p3 * r3;
    }
    for (; j < hi; ++j) {
        const int s = esrc[j];
        float e = as_[s] + ad;
        e = (e > 0.f) ? e : 0.2f * e;
        const float p = __expf(e - m) * inv;
        acc += p * h[(size_t)s * 64 + lane];
    }

    out[(size_t)n * 64 + lane] = acc + bias[lane];
}

// ---------------------------------------------------------------------------
extern "C" void kernel_launch(void* const* d_in, const int* in_sizes, int n_in,
                              void* d_out, int out_size, void* d_ws, size_t ws_size,
                              hipStream_t stream) {
    const float* x    = (const float*)d_in[0];
    const int*   edge = (const int*)d_in[1];
    const int N = in_sizes[0] / IN_DIM;
    const int E = in_sizes[1] / 2;
    const int Mp = ((N + 127) / 128) * 128;

    const float* W[4]; const float* As[4]; const float* Ad[4]; const float* Bb[4];
    for (int i = 0; i < 4; ++i) {
        W[i]  = (const float*)d_in[2 + 4 * i];
        As[i] = (const float*)d_in[3 + 4 * i];
        Ad[i] = (const float*)d_in[4 + 4 * i];
        Bb[i] = (const float*)d_in[5 + 4 * i];
    }

    char* ws = (char*)d_ws;
    auto alloc = [&](size_t bytes) {
        char* p = ws;
        ws += (bytes + 255) & ~(size_t)255;
        return p;
    };
    _Float16*       h16   = (_Float16*)alloc((size_t)4 * Mp * 256 * 2);    // h, fp16 head-major
    float*          bufA  = (float*)alloc((size_t)Mp * OUT_DIM * 4);       // layer-3 GEMM out
    unsigned short* Xhi   = (unsigned short*)alloc((size_t)Mp * 1024 * 2);
    unsigned short* Xlo   = (unsigned short*)alloc((size_t)Mp * 1024 * 2);
    unsigned short* Wthi  = (unsigned short*)alloc((size_t)1024 * 1024 * 2);
    unsigned short* Wtlo  = (unsigned short*)alloc((size_t)1024 * 1024 * 2);
    float*          as_buf = (float*)alloc((size_t)N * 4 * 4);
    float*          ad_buf = (float*)alloc((size_t)N * 4 * 4);
    int*            deg    = (int*)alloc((size_t)(N + 1) * 4);
    int*            offs   = (int*)alloc((size_t)(N + 1) * 4);
    int*            cursor = (int*)alloc((size_t)N * 4);
    int*            esrc   = (int*)alloc((size_t)E * 4);
    (void)ws_size;

    const int* e_src = edge;
    const int* e_dst = edge + E;

    // ---- CSR build ----
    hipMemsetAsync(deg, 0, (size_t)N * 4, stream);
    count_deg_kernel<<<(E + 255) / 256, 256, 0, stream>>>(e_dst, deg, E);
    scan_offsets_kernel<<<1, 1024, 0, stream>>>(deg, offs, N);
    hipMemsetAsync(cursor, 0, (size_t)N * 4, stream);
    scatter_edges_kernel<<<(E + 255) / 256, 256, 0, stream>>>(e_src, e_dst, offs, cursor, esrc, E);

    // ---- zero only the pad rows of the split A views ----
    hipMemsetAsync((char*)Xhi + (size_t)N * 256, 0, (size_t)(Mp - N) * 256, stream);
    hipMemsetAsync((char*)Xlo + (size_t)N * 256, 0, (size_t)(Mp - N) * 256, stream);
    hipMemsetAsync((char*)Xhi + (size_t)N * 2048, 0, (size_t)(Mp - N) * 2048, stream);
    hipMemsetAsync((char*)Xlo + (size_t)N * 2048, 0, (size_t)(Mp - N) * 2048, stream);

    // ---- layer 0 input split ----
    {
        size_t n4 = (size_t)N * IN_DIM / 4;
        split_x_kernel<<<(unsigned)((n4 + 255) / 256), 256, 0, stream>>>(x, Xhi, Xlo, n4);
    }

    const dim3 tblk(32, 8);
    const int gx = Mp / 128;
    const size_t hstride16 = (size_t)Mp * 256;
    const size_t abytes = (size_t)N * 4 * 4;

    // ---- Layer 0 ----
    transpose_split_kernel<<<dim3(IN_DIM / 32, 1024 / 32), tblk, 0, stream>>>(W[0], Wthi, Wtlo, IN_DIM, 1024);
    hipMemsetAsync(as_buf, 0, abytes, stream);
    hipMemsetAsync(ad_buf, 0, abytes, stream);
    gemm_split_mfma<<<dim3(gx, 8), 256, 0, stream>>>(Xhi, Xlo, Wthi, Wtlo, nullptr, h16, 1024, IN_DIM, hstride16,
                                                     As[0], Ad[0], as_buf, ad_buf, N);
    spmm16_kernel<<<dim3(N, 4), 64, 0, stream>>>(
        h16, as_buf, ad_buf, offs, esrc, Bb[0], N, Mp, Xhi, Xlo);

    // ---- Layers 1,2 ----
    for (int l = 1; l <= 2; ++l) {
        transpose_split_kernel<<<dim3(1024 / 32, 1024 / 32), tblk, 0, stream>>>(W[l], Wthi, Wtlo, 1024, 1024);
        hipMemsetAsync(as_buf, 0, abytes, stream);
        hipMemsetAsync(ad_buf, 0, abytes, stream);
        gemm_split_mfma<<<dim3(gx, 8), 256, 0, stream>>>(Xhi, Xlo, Wthi, Wtlo, nullptr, h16, 1024, 1024, hstride16,
                                                         As[l], Ad[l], as_buf, ad_buf, N);
        spmm16_kernel<<<dim3(N, 4), 64, 0, stream>>>(
            h16, as_buf, ad_buf, offs, esrc, Bb[l], N, Mp, Xhi, Xlo);
    }

    // ---- Layer 3: K=1024 -> h(64), 1 head, fp32 out ----
    hipMemsetAsync(Wthi, 0, (size_t)128 * 1024 * 2, stream);
    hipMemsetAsync(Wtlo, 0, (size_t)128 * 1024 * 2, stream);
    transpose_split_kernel<<<dim3(1024 / 32, OUT_DIM / 32), tblk, 0, stream>>>(W[3], Wthi, Wtlo, 1024, OUT_DIM);
    gemm_split_mfma<<<dim3(gx, 1), 256, 0, stream>>>(Xhi, Xlo, Wthi, Wtlo, bufA, nullptr, OUT_DIM, 1024, 0,
                                                     nullptr, nullptr, nullptr, nullptr, N);
    alpha32_kernel<<<N, 64, 0, stream>>>(bufA, As[3], Ad[3], as_buf, ad_buf, N);
    spmm32_kernel<<<N, 64, 0, stream>>>(
        bufA, as_buf, ad_buf, offs, esrc, Bb[3], N, (float*)d_out);
}

// Round 8
// 605.976 us; speedup vs baseline: 1.3028x; 1.1926x over previous
//
#include <hip/hip_runtime.h>
#include <math.h>

#define IN_DIM 128
#define OUT_DIM 64

typedef __attribute__((ext_vector_type(8))) _Float16 f16x8;
typedef __attribute__((ext_vector_type(4))) float f32x4;
typedef __attribute__((ext_vector_type(4))) _Float16 half4;

#define WSCALE 32.0f
#define WINV   (1.0f / 32.0f)

__device__ __forceinline__ void async_copy16(void* lds, const void* g) {
    __builtin_amdgcn_global_load_lds(
        (const __attribute__((address_space(1))) unsigned int*)g,
        (__attribute__((address_space(3))) unsigned int*)lds, 16, 0, 0);
}

// ---------------------------------------------------------------------------
// CSR build (by dst). Self-loops handled implicitly downstream.
// ---------------------------------------------------------------------------
__global__ void count_deg_kernel(const int* __restrict__ dst, int* __restrict__ deg, int e) {
    int i = blockIdx.x * blockDim.x + threadIdx.x;
    if (i < e) atomicAdd(&deg[dst[i]], 1);
}

__global__ __launch_bounds__(1024)
void scan_offsets_kernel(const int* __restrict__ deg, int* __restrict__ offs, int n) {
    __shared__ int partial[1024];
    const int tid = threadIdx.x;
    const int chunk = (n + 1023) / 1024;
    const int lo = tid * chunk;
    const int hi = min(lo + chunk, n);
    int s = 0;
    for (int i = lo; i < hi; ++i) s += deg[i];
    partial[tid] = s;
    __syncthreads();
    for (int d = 1; d < 1024; d <<= 1) {
        int v = (tid >= d) ? partial[tid - d] : 0;
        __syncthreads();
        partial[tid] += v;
        __syncthreads();
    }
    int run = (tid == 0) ? 0 : partial[tid - 1];
    for (int i = lo; i < hi; ++i) { offs[i] = run; run += deg[i]; }
    if (hi == n) offs[n] = run;
}

__global__ void scatter_edges_kernel(const int* __restrict__ src, const int* __restrict__ dst,
                                     const int* __restrict__ offs, int* __restrict__ cursor,
                                     int* __restrict__ esrc, int e) {
    int i = blockIdx.x * blockDim.x + threadIdx.x;
    if (i < e) {
        int d = dst[i];
        int pos = offs[d] + atomicAdd(&cursor[d], 1);
        esrc[pos] = src[i];
    }
}

// ---------------------------------------------------------------------------
// x fp32 -> fp16 (layer-0 GEMM A operand).
// ---------------------------------------------------------------------------
__global__ void x_to_f16_kernel(const float* __restrict__ x, _Float16* __restrict__ out, size_t n4) {
    size_t i = (size_t)blockIdx.x * blockDim.x + threadIdx.x;
    if (i >= n4) return;
    float4 v = *(const float4*)&x[i * 4];
    half4 h;
    h[0] = (_Float16)v.x; h[1] = (_Float16)v.y; h[2] = (_Float16)v.z; h[3] = (_Float16)v.w;
    *(half4*)&out[i * 4] = h;
}

// ---------------------------------------------------------------------------
// W [K][Nc] fp32 -> Wt hi/lo [Nc][K] fp16 (transposed), scaled x32 so the
// lo residual stays out of fp16-subnormal range (undone by WINV in epilogue).
// ---------------------------------------------------------------------------
__global__ __launch_bounds__(256)
void transpose_split_f16(const float* __restrict__ W,
                         _Float16* __restrict__ hi, _Float16* __restrict__ lo,
                         int K, int Nc) {
    __shared__ float t[32][33];
    const int k0 = blockIdx.x * 32, n0 = blockIdx.y * 32;
    const int tx = threadIdx.x, ty = threadIdx.y;   // (32,8)
    #pragma unroll
    for (int j = 0; j < 32; j += 8)
        t[ty + j][tx] = W[(size_t)(k0 + ty + j) * Nc + n0 + tx];
    __syncthreads();
    #pragma unroll
    for (int j = 0; j < 32; j += 8) {
        float v = t[tx][ty + j] * WSCALE;
        _Float16 h = (_Float16)v;
        hi[(size_t)(n0 + ty + j) * K + k0 + tx] = h;
        lo[(size_t)(n0 + ty + j) * K + k0 + tx] = (_Float16)(v - (float)h);
    }
}

// ---------------------------------------------------------------------------
// fp16 MFMA GEMM: C = A[Mp][K] * (Whi+Wlo)[Ncp][K]^T * WINV.
// A single fp16 (2^-11), W split-fp16 (2^-22): 2 MFMAs per acc.
// 128x128 tile, BK=64, 4 waves, 16x16x32_f16; LDS 48KB -> 3 blocks/CU.
// Grid: x = col-group (fast axis -> concurrent blocks share A row panels,
// A stays L2/L3-resident), y = row panel.
// Output: C16 head-major [4][Mp][256] + fused alpha (layers 0-2),
// or fp32 row-major guarded (layer 3).
// ---------------------------------------------------------------------------
__global__ __launch_bounds__(256, 3)
void gemm_f16_mfma(const _Float16* __restrict__ A,
                   const _Float16* __restrict__ Whi, const _Float16* __restrict__ Wlo,
                   float* __restrict__ C, _Float16* __restrict__ C16,
                   int Nc, int K, size_t hstride16,
                   const float* __restrict__ Asrc, const float* __restrict__ Adst,
                   float* __restrict__ as_out, float* __restrict__ ad_out, int Nrows) {
    __shared__ char smem[49152];          // 3 tiles x [128 rows][128 B]
    char* sA  = smem;
    char* sBh = smem + 16384;
    char* sBl = smem + 32768;

    const int tid = threadIdx.x;
    const int w = tid >> 6;
    const int lane = tid & 63;
    const int wr = w >> 1, wc = w & 1;
    const int bcol = blockIdx.x * 128;    // fast axis: col group
    const int brow = blockIdx.y * 128;    // slow axis: row panel

    const size_t rb = (size_t)K * 2;

    int rr[4], bs[4], ldso[4];
    #pragma unroll
    for (int i = 0; i < 4; ++i) {
        int d = w * 4096 + i * 1024 + lane * 16;
        ldso[i] = d;
        rr[i] = d >> 7;
        int b = d & 127;
        bs[i] = b ^ ((rr[i] & 7) << 4);
    }

    const char* gA  = (const char*)A   + (size_t)brow * rb;
    const char* gBh = (const char*)Whi + (size_t)bcol * rb;
    const char* gBl = (const char*)Wlo + (size_t)bcol * rb;

    f32x4 acc[4][4];
    #pragma unroll
    for (int i = 0; i < 4; ++i)
        #pragma unroll
        for (int j = 0; j < 4; ++j) acc[i][j] = (f32x4)0.f;

    for (int k0 = 0; k0 < K; k0 += 64) {
        __syncthreads();
        const size_t kb = (size_t)k0 * 2;
        #pragma unroll
        for (int i = 0; i < 4; ++i) {
            const size_t goff = (size_t)rr[i] * rb + kb + bs[i];
            async_copy16(sA  + ldso[i], gA  + goff);
            async_copy16(sBh + ldso[i], gBh + goff);
            async_copy16(sBl + ldso[i], gBl + goff);
        }
        __syncthreads();

        #pragma unroll
        for (int kk = 0; kk < 2; ++kk) {
            f16x8 a[4], bh[4], bl[4];
            const int kbyte = kk * 64 + ((lane >> 4) * 16);
            #pragma unroll
            for (int f = 0; f < 4; ++f) {
                const int ra = wr * 64 + f * 16 + (lane & 15);
                const int offA = ra * 128 + (kbyte ^ ((ra & 7) << 4));
                a[f] = *(const f16x8*)(sA + offA);
                const int rbn = wc * 64 + f * 16 + (lane & 15);
                const int offB = rbn * 128 + (kbyte ^ ((rbn & 7) << 4));
                bh[f] = *(const f16x8*)(sBh + offB);
                bl[f] = *(const f16x8*)(sBl + offB);
            }
            #pragma unroll
            for (int m = 0; m < 4; ++m)
                #pragma unroll
                for (int n = 0; n < 4; ++n) {
                    acc[m][n] = __builtin_amdgcn_mfma_f32_16x16x32_f16(a[m], bh[n], acc[m][n], 0, 0, 0);
                    acc[m][n] = __builtin_amdgcn_mfma_f32_16x16x32_f16(a[m], bl[n], acc[m][n], 0, 0, 0);
                }
        }
    }

    // undo the W x32 scale
    #pragma unroll
    for (int m = 0; m < 4; ++m)
        #pragma unroll
        for (int n = 0; n < 4; ++n) acc[m][n] *= WINV;

    const int rowb = brow + wr * 64 + ((lane >> 4) * 4);
    const int colb = bcol + wc * 64 + (lane & 15);
    if (C16) {
        #pragma unroll
        for (int m = 0; m < 4; ++m)
            #pragma unroll
            for (int n = 0; n < 4; ++n) {
                const int col = colb + n * 16;
                const size_t base = (size_t)(col >> 8) * hstride16 + (size_t)(col & 255);
                #pragma unroll
                for (int j = 0; j < 4; ++j)
                    C16[base + (size_t)(rowb + m * 16 + j) * 256] = (_Float16)acc[m][n][j];
            }
        if (as_out) {
            // fused alpha: dot of exact fp32 acc tile with a_src/a_dst
            const int lcol = lane & 15;
            const int cb = bcol + wc * 64;
            const int head = cb >> 8;
            float as4[4], ad4[4];
            #pragma unroll
            for (int n = 0; n < 4; ++n) {
                as4[n] = Asrc[cb + n * 16 + lcol];
                ad4[n] = Adst[cb + n * 16 + lcol];
            }
            #pragma unroll
            for (int m = 0; m < 4; ++m)
                #pragma unroll
                for (int j = 0; j < 4; ++j) {
                    float ps = acc[m][0][j] * as4[0] + acc[m][1][j] * as4[1]
                             + acc[m][2][j] * as4[2] + acc[m][3][j] * as4[3];
                    float pd = acc[m][0][j] * ad4[0] + acc[m][1][j] * ad4[1]
                             + acc[m][2][j] * ad4[2] + acc[m][3][j] * ad4[3];
                    #pragma unroll
                    for (int o = 1; o < 16; o <<= 1) {
                        ps += __shfl_xor(ps, o);
                        pd += __shfl_xor(pd, o);
                    }
                    if (lcol == 0) {
                        const int row = rowb + m * 16 + j;
                        if (row < Nrows) {
                            atomicAdd(&as_out[(size_t)head * Nrows + row], ps);
                            atomicAdd(&ad_out[(size_t)head * Nrows + row], pd);
                        }
                    }
                }
        }
    } else {
        #pragma unroll
        for (int m = 0; m < 4; ++m)
            #pragma unroll
            for (int n = 0; n < 4; ++n) {
                const int col = colb + n * 16;
                if (col < Nc) {
                    #pragma unroll
                    for (int j = 0; j < 4; ++j)
                        C[(size_t)(rowb + m * 16 + j) * Nc + col] = acc[m][n][j];
                }
            }
    }
}

// ---------------------------------------------------------------------------
// fp32 alpha for layer 3 (1 head, CH=64)
// ---------------------------------------------------------------------------
__global__ void alpha32_kernel(const float* __restrict__ h, const float* __restrict__ a_src,
                               const float* __restrict__ a_dst,
                               float* __restrict__ as_out, float* __restrict__ ad_out, int N) {
    const int n = blockIdx.x;
    const int lane = threadIdx.x;
    float v = h[(size_t)n * 64 + lane];
    float ss = v * a_src[lane];
    float sd = v * a_dst[lane];
    #pragma unroll
    for (int o = 32; o > 0; o >>= 1) { ss += __shfl_down(ss, o); sd += __shfl_down(sd, o); }
    if (lane == 0) {
        as_out[n] = ss;
        ad_out[n] = sd;
    }
}

// ---------------------------------------------------------------------------
// Fused SpMM with in-wave softmax stats. One wave per (node, head):
// wave-parallel exact max & denom over edge logits, then unroll-4 weighted
// gather of fp16 rows. Epilogue: +bias, ELU, single fp16 write (next GEMM A).
// ---------------------------------------------------------------------------
__global__ __launch_bounds__(64)
void spmm16_kernel(const _Float16* __restrict__ h,   // [4][hm][256]
                   const float* __restrict__ as_,    // [4][N]
                   const float* __restrict__ ad_,
                   const int* __restrict__ offs, const int* __restrict__ esrc,
                   const float* __restrict__ bias,   // [4*256]
                   int N, int hm,
                   _Float16* __restrict__ out16) {   // [Mp][1024] row-major
    const int n = blockIdx.x;
    const int w = blockIdx.y;
    const int lane = threadIdx.x;

    const _Float16* hw = h + (size_t)w * hm * 256;
    const float* asw = as_ + (size_t)w * N;
    const float ad  = ad_[(size_t)w * N + n];

    float e0 = asw[n] + ad;
    e0 = (e0 > 0.f) ? e0 : 0.2f * e0;
    const int lo = offs[n], hi = offs[n + 1];

    // ---- wave-parallel stats: exact max, then denom ----
    float lmax = e0;
    for (int j = lo + lane; j < hi; j += 64) {
        float e = asw[esrc[j]] + ad;
        e = (e > 0.f) ? e : 0.2f * e;
        lmax = fmaxf(lmax, e);
    }
    #pragma unroll
    for (int o = 32; o > 0; o >>= 1) lmax = fmaxf(lmax, __shfl_xor(lmax, o));
    const float m = lmax;

    float lsum = (lane == 0) ? __expf(e0 - m) : 0.f;
    for (int j = lo + lane; j < hi; j += 64) {
        float e = asw[esrc[j]] + ad;
        e = (e > 0.f) ? e : 0.2f * e;
        lsum += __expf(e - m);
    }
    #pragma unroll
    for (int o = 32; o > 0; o >>= 1) lsum += __shfl_xor(lsum, o);
    const float inv = 1.0f / (lsum + 1e-16f);

    // ---- weighted gather ----
    float acc0, acc1, acc2, acc3;
    {
        const float p0 = __expf(e0 - m) * inv;
        half4 t = *(const half4*)(hw + (size_t)n * 256 + lane * 4);
        acc0 = p0 * (float)t[0]; acc1 = p0 * (float)t[1];
        acc2 = p0 * (float)t[2]; acc3 = p0 * (float)t[3];
    }

    int j = lo;
    for (; j + 4 <= hi; j += 4) {
        const int s0 = esrc[j], s1 = esrc[j + 1], s2 = esrc[j + 2], s3 = esrc[j + 3];
        const half4 r0 = *(const half4*)(hw + (size_t)s0 * 256 + lane * 4);
        const half4 r1 = *(const half4*)(hw + (size_t)s1 * 256 + lane * 4);
        const half4 r2 = *(const half4*)(hw + (size_t)s2 * 256 + lane * 4);
        const half4 r3 = *(const half4*)(hw + (size_t)s3 * 256 + lane * 4);
        float e, p0, p1, p2, p3;
        e = asw[s0] + ad; e = (e > 0.f) ? e : 0.2f * e; p0 = __expf(e - m) * inv;
        e = asw[s1] + ad; e = (e > 0.f) ? e : 0.2f * e; p1 = __expf(e - m) * inv;
        e = asw[s2] + ad; e = (e > 0.f) ? e : 0.2f * e; p2 = __expf(e - m) * inv;
        e = asw[s3] + ad; e = (e > 0.f) ? e : 0.2f * e; p3 = __expf(e - m) * inv;
        acc0 += p0 * (float)r0[0] + p1 * (float)r1[0] + p2 * (float)r2[0] + p3 * (float)r3[0];
        acc1 += p0 * (float)r0[1] + p1 * (float)r1[1] + p2 * (float)r2[1] + p3 * (float)r3[1];
        acc2 += p0 * (float)r0[2] + p1 * (float)r1[2] + p2 * (float)r2[2] + p3 * (float)r3[2];
        acc3 += p0 * (float)r0[3] + p1 * (float)r1[3] + p2 * (float)r2[3] + p3 * (float)r3[3];
    }
    for (; j < hi; ++j) {
        const int s = esrc[j];
        float e = asw[s] + ad;
        e = (e > 0.f) ? e : 0.2f * e;
        const float p = __expf(e - m) * inv;
        half4 t = *(const half4*)(hw + (size_t)s * 256 + lane * 4);
        acc0 += p * (float)t[0]; acc1 += p * (float)t[1];
        acc2 += p * (float)t[2]; acc3 += p * (float)t[3];
    }

    float v0 = acc0 + bias[w * 256 + lane * 4 + 0];
    float v1 = acc1 + bias[w * 256 + lane * 4 + 1];
    float v2 = acc2 + bias[w * 256 + lane * 4 + 2];
    float v3 = acc3 + bias[w * 256 + lane * 4 + 3];
    v0 = (v0 > 0.f) ? v0 : (__expf(v0) - 1.0f);
    v1 = (v1 > 0.f) ? v1 : (__expf(v1) - 1.0f);
    v2 = (v2 > 0.f) ? v2 : (__expf(v2) - 1.0f);
    v3 = (v3 > 0.f) ? v3 : (__expf(v3) - 1.0f);

    half4 hv;
    hv[0] = (_Float16)v0; hv[1] = (_Float16)v1;
    hv[2] = (_Float16)v2; hv[3] = (_Float16)v3;
    *(half4*)&out16[(size_t)n * 1024 + (size_t)w * 256 + lane * 4] = hv;
}

// ---------------------------------------------------------------------------
// Final layer: fp32 h [N][64], 1 head, no ELU, fp32 out. Fused stats.
// ---------------------------------------------------------------------------
__global__ __launch_bounds__(64)
void spmm32_kernel(const float* __restrict__ h,
                   const float* __restrict__ as_, const float* __restrict__ ad_,
                   const int* __restrict__ offs, const int* __restrict__ esrc,
                   const float* __restrict__ bias,
                   int N, float* __restrict__ out) {
    const int n = blockIdx.x;
    const int lane = threadIdx.x;

    const float ad  = ad_[n];
    float e0 = as_[n] + ad;
    e0 = (e0 > 0.f) ? e0 : 0.2f * e0;
    const int lo = offs[n], hi = offs[n + 1];

    float lmax = e0;
    for (int j = lo + lane; j < hi; j += 64) {
        float e = as_[esrc[j]] + ad;
        e = (e > 0.f) ? e : 0.2f * e;
        lmax = fmaxf(lmax, e);
    }
    #pragma unroll
    for (int o = 32; o > 0; o >>= 1) lmax = fmaxf(lmax, __shfl_xor(lmax, o));
    const float m = lmax;

    float lsum = (lane == 0) ? __expf(e0 - m) : 0.f;
    for (int j = lo + lane; j < hi; j += 64) {
        float e = as_[esrc[j]] + ad;
        e = (e > 0.f) ? e : 0.2f * e;
        lsum += __expf(e - m);
    }
    #pragma unroll
    for (int o = 32; o > 0; o >>= 1) lsum += __shfl_xor(lsum, o);
    const float inv = 1.0f / (lsum + 1e-16f);

    float acc;
    {
        const float p0 = __expf(e0 - m) * inv;
        acc = p0 * h[(size_t)n * 64 + lane];
    }

    int j = lo;
    for (; j + 4 <= hi; j += 4) {
        const int s0 = esrc[j], s1 = esrc[j + 1], s2 = esrc[j + 2], s3 = esrc[j + 3];
        const float r0 = h[(size_t)s0 * 64 + lane];
        const float r1 = h[(size_t)s1 * 64 + lane];
        const float r2 = h[(size_t)s2 * 64 + lane];
        const float r3 = h[(size_t)s3 * 64 + lane];
        float e, p0, p1, p2, p3;
        e = as_[s0] + ad; e = (e > 0.f) ? e : 0.2f * e; p0 = __expf(e - m) * inv;
        e = as_[s1] + ad; e = (e > 0.f) ? e : 0.2f * e; p1 = __expf(e - m) * inv;
        e = as_[s2] + ad; e = (e > 0.f) ? e : 0.2f * e; p2 = __expf(e - m) * inv;
        e = as_[s3] + ad; e = (e > 0.f) ? e : 0.2f * e; p3 = __expf(e - m) * inv;
        acc += p0 * r0 + p1 * r1 + p2 * r2 + p3 * r3;
    }
    for (; j < hi; ++j) {
        const int s = esrc[j];
        float e = as_[s] + ad;
        e = (e > 0.f) ? e : 0.2f * e;
        const float p = __expf(e - m) * inv;
        acc += p * h[(size_t)s * 64 + lane];
    }

    out[(size_t)n * 64 + lane] = acc + bias[lane];
}

// ---------------------------------------------------------------------------
extern "C" void kernel_launch(void* const* d_in, const int* in_sizes, int n_in,
                              void* d_out, int out_size, void* d_ws, size_t ws_size,
                              hipStream_t stream) {
    const float* x    = (const float*)d_in[0];
    const int*   edge = (const int*)d_in[1];
    const int N = in_sizes[0] / IN_DIM;
    const int E = in_sizes[1] / 2;
    const int Mp = ((N + 127) / 128) * 128;

    const float* W[4]; const float* As[4]; const float* Ad[4]; const float* Bb[4];
    for (int i = 0; i < 4; ++i) {
        W[i]  = (const float*)d_in[2 + 4 * i];
        As[i] = (const float*)d_in[3 + 4 * i];
        Ad[i] = (const float*)d_in[4 + 4 * i];
        Bb[i] = (const float*)d_in[5 + 4 * i];
    }

    char* ws = (char*)d_ws;
    auto alloc = [&](size_t bytes) {
        char* p = ws;
        ws += (bytes + 255) & ~(size_t)255;
        return p;
    };
    _Float16*  h16   = (_Float16*)alloc((size_t)4 * Mp * 256 * 2);   // GEMM out, fp16 head-major
    _Float16*  X16   = (_Float16*)alloc((size_t)Mp * 1024 * 2);      // layer input (GEMM A), fp16
    float*     bufA  = (float*)alloc((size_t)Mp * OUT_DIM * 4);      // layer-3 GEMM out
    _Float16*  Wthi  = (_Float16*)alloc((size_t)1024 * 1024 * 2);
    _Float16*  Wtlo  = (_Float16*)alloc((size_t)1024 * 1024 * 2);
    float*     as_buf = (float*)alloc((size_t)N * 4 * 4);
    float*     ad_buf = (float*)alloc((size_t)N * 4 * 4);
    int*       deg    = (int*)alloc((size_t)(N + 1) * 4);
    int*       offs   = (int*)alloc((size_t)(N + 1) * 4);
    int*       cursor = (int*)alloc((size_t)N * 4);
    int*       esrc   = (int*)alloc((size_t)E * 4);
    (void)ws_size;

    const int* e_src = edge;
    const int* e_dst = edge + E;

    // ---- CSR build ----
    hipMemsetAsync(deg, 0, (size_t)N * 4, stream);
    count_deg_kernel<<<(E + 255) / 256, 256, 0, stream>>>(e_dst, deg, E);
    scan_offsets_kernel<<<1, 1024, 0, stream>>>(deg, offs, N);
    hipMemsetAsync(cursor, 0, (size_t)N * 4, stream);
    scatter_edges_kernel<<<(E + 255) / 256, 256, 0, stream>>>(e_src, e_dst, offs, cursor, esrc, E);

    // ---- zero pad rows of the X16 views ----
    // layer-0 view [Mp][128] fp16: rows are 256 B
    hipMemsetAsync((char*)X16 + (size_t)N * 256, 0, (size_t)(Mp - N) * 256, stream);
    // layers 1-3 view [Mp][1024] fp16: rows are 2048 B
    hipMemsetAsync((char*)X16 + (size_t)N * 2048, 0, (size_t)(Mp - N) * 2048, stream);

    // ---- layer 0 input -> fp16 ----
    {
        size_t n4 = (size_t)N * IN_DIM / 4;
        x_to_f16_kernel<<<(unsigned)((n4 + 255) / 256), 256, 0, stream>>>(x, X16, n4);
    }

    const dim3 tblk(32, 8);
    const int gx = Mp / 128;
    const size_t hstride16 = (size_t)Mp * 256;
    const size_t abytes = (size_t)N * 4 * 4;

    // ---- Layer 0 ----
    transpose_split_f16<<<dim3(IN_DIM / 32, 1024 / 32), tblk, 0, stream>>>(W[0], Wthi, Wtlo, IN_DIM, 1024);
    hipMemsetAsync(as_buf, 0, abytes, stream);
    hipMemsetAsync(ad_buf, 0, abytes, stream);
    gemm_f16_mfma<<<dim3(8, gx), 256, 0, stream>>>(X16, Wthi, Wtlo, nullptr, h16, 1024, IN_DIM, hstride16,
                                                   As[0], Ad[0], as_buf, ad_buf, N);
    spmm16_kernel<<<dim3(N, 4), 64, 0, stream>>>(
        h16, as_buf, ad_buf, offs, esrc, Bb[0], N, Mp, X16);

    // ---- Layers 1,2 ----
    for (int l = 1; l <= 2; ++l) {
        transpose_split_f16<<<dim3(1024 / 32, 1024 / 32), tblk, 0, stream>>>(W[l], Wthi, Wtlo, 1024, 1024);
        hipMemsetAsync(as_buf, 0, abytes, stream);
        hipMemsetAsync(ad_buf, 0, abytes, stream);
        gemm_f16_mfma<<<dim3(8, gx), 256, 0, stream>>>(X16, Wthi, Wtlo, nullptr, h16, 1024, 1024, hstride16,
                                                       As[l], Ad[l], as_buf, ad_buf, N);
        spmm16_kernel<<<dim3(N, 4), 64, 0, stream>>>(
            h16, as_buf, ad_buf, offs, esrc, Bb[l], N, Mp, X16);
    }

    // ---- Layer 3: K=1024 -> h(64), 1 head, fp32 out ----
    hipMemsetAsync(Wthi, 0, (size_t)128 * 1024 * 2, stream);   // zero rows 0..127 (cols 64..127 stay 0)
    hipMemsetAsync(Wtlo, 0, (size_t)128 * 1024 * 2, stream);
    transpose_split_f16<<<dim3(1024 / 32, OUT_DIM / 32), tblk, 0, stream>>>(W[3], Wthi, Wtlo, 1024, OUT_DIM);
    gemm_f16_mfma<<<dim3(1, gx), 256, 0, stream>>>(X16, Wthi, Wtlo, bufA, nullptr, OUT_DIM, 1024, 0,
                                                   nullptr, nullptr, nullptr, nullptr, N);
    alpha32_kernel<<<N, 64, 0, stream>>>(bufA, As[3], Ad[3], as_buf, ad_buf, N);
    spmm32_kernel<<<N, 64, 0, stream>>>(
        bufA, as_buf, ad_buf, offs, esrc, Bb[3], N, (float*)d_out);
}